// Round 7
// baseline (101.333 us; speedup 1.0000x reference)
//
#include <hip/hip_runtime.h>
#include <math.h>

#define TD 128   // feature dimension
#define BT 64    // fallback tile rows
#define TB 256   // tile rows per block (256x256 tiles)
#define GRID 256 // persistent blocks, 1 per CU

typedef _Float16 half8 __attribute__((ext_vector_type(8)));
typedef _Float16 half2v __attribute__((ext_vector_type(2)));
typedef float f32x4 __attribute__((ext_vector_type(4)));

// K = exp(-d2/(2*10^2)) = 2^(C2*d2);  C2 = -1/(200*ln2)
#define C2f   (-0.0072134752044448f)
#define M2C2f (0.0144269504088896f)   /* -2*C2 */

#if __has_builtin(__builtin_amdgcn_exp2f)
#define EXP2F(x) __builtin_amdgcn_exp2f(x)
#else
#define EXP2F(x) exp2f(x)
#endif

// LDS layout (bytes): 4 half-K panels [256 rows][64 fp16 = 128B] + 2 En slices
#define LA0 0
#define LA1 32768
#define LB0 65536
#define LB1 98304
#define LEA 131072
#define LEB 132096
#define LDS_TOT 133120

#define SCHEDB() __builtin_amdgcn_sched_barrier(0)

__device__ __forceinline__ void gload16(const void* g, void* l) {
    __builtin_amdgcn_global_load_lds(
        (const __attribute__((address_space(1))) void*)g,
        (__attribute__((address_space(3))) void*)l, 16, 0, 0);
}

__device__ __forceinline__ void decode_tile(int t, int T, int& bi, int& bj) {
    double bguess = (2.0 * T + 1.0 -
                     sqrt((2.0 * T + 1.0) * (2.0 * T + 1.0) - 8.0 * (double)t)) * 0.5;
    int b = (int)bguess;
    if (b < 0) b = 0;
    if (b > T - 1) b = T - 1;
    while ((b + 1) * T - ((b + 1) * b) / 2 <= t) ++b;
    while (b * T - (b * (b - 1)) / 2 > t) --b;
    bi = b;
    bj = b + (t - (b * T - (b * (b - 1)) / 2));
}

// ---------------------------------------------------------------------------
// Prologue: Z -> fp16 + En[r] = exp2(C2*||f16(z_r)||^2)
// ---------------------------------------------------------------------------
__global__ __launch_bounds__(256) void cvt_norms_kernel(const float* __restrict__ X,
                                                        const float* __restrict__ Y,
                                                        int n, int tot,
                                                        _Float16* __restrict__ Z16,
                                                        float* __restrict__ En) {
    const int wid  = (blockIdx.x * 256 + threadIdx.x) >> 6;
    const int lane = threadIdx.x & 63;
    if (wid >= tot) return;
    const float* row = (wid < n) ? (X + (size_t)wid * TD) : (Y + (size_t)(wid - n) * TD);
    float2 v = *reinterpret_cast<const float2*>(row + lane * 2);
    _Float16 hx = (_Float16)v.x;
    _Float16 hy = (_Float16)v.y;
    half2v h2 = {hx, hy};
    *reinterpret_cast<half2v*>(Z16 + (size_t)wid * TD + lane * 2) = h2;
    float fx = (float)hx, fy = (float)hy;
    float s = fmaf(fx, fx, fy * fy);
#pragma unroll
    for (int off = 32; off > 0; off >>= 1) s += __shfl_down(s, off, 64);
    if (lane == 0) En[wid] = EXP2F(C2f * s);
}

// ---------------------------------------------------------------------------
// Main: persistent blocks (1/CU), 1024 threads / 16 waves.
// amdgpu_waves_per_eu(4,4) pins EXACTLY 4 waves/SIMD -> 128-VGPR budget
// (r6 regression: launch_bounds min-only let the compiler target 8/EU ->
// 64 VGPR -> scratch spills, FETCH 83MB).
// Each wave: 64x64 out via 4x4 frags of mfma_f32_16x16x32_f16.  K=128 in
// two 64-halves, 4 LDS buffers; staging issues hidden under compute;
// counted vmcnt (never 0 until last tile); per-wave double accumulator.
// ---------------------------------------------------------------------------
__global__ __launch_bounds__(1024)
__attribute__((amdgpu_waves_per_eu(4, 4)))
void mmd_pipe_kernel(const _Float16* __restrict__ Z16,
                     const float* __restrict__ En,
                     double* __restrict__ partials,
                     int n, int m, int T, int ntiles) {
    __shared__ char lds[LDS_TOT];

    const int tid = threadIdx.x;
    const int l = tid & 63;
    const int w = tid >> 6;           // wave 0..15
    const int wrow = (w >> 2) * 64;   // 0,64,128,192
    const int wcol = (w & 3) * 64;    // 0,64,128,192
    const int lr = l & 15;            // row/col within 16-block
    const int kq = l >> 4;            // k-quarter
    const int swz = lr & 7;

    // staging geometry: chunk = 1KB = 8 rows x 128B (one K-half)
    const int rsub = l >> 3;          // row within 8-row chunk
    const int psl  = l & 7;           // phys slot
    const int srcsw = (psl ^ rsub) << 4;   // inverse-swizzled src byte offset

    double acc_d = 0.0;
    int it = blockIdx.x;

    if (it < ntiles) {
        int bi, bj;
        decode_tile(it, T, bi, bj);
        const char* gA = (const char*)Z16 + (size_t)bi * (TB * TD * 2);
        const char* gB = (const char*)Z16 + (size_t)bj * (TB * TD * 2);

        // prologue: stage S0 (half0) + S1 (half1) + En of first tile
#pragma unroll
        for (int q = 0; q < 2; ++q) {
            const int chunk = w * 2 + q;
            const int row = chunk * 8 + rsub;
            gload16(gA + (size_t)row * 256 + srcsw, lds + LA0 + chunk * 1024);
            gload16(gB + (size_t)row * 256 + srcsw, lds + LB0 + chunk * 1024);
        }
#pragma unroll
        for (int q = 0; q < 2; ++q) {
            const int chunk = w * 2 + q;
            const int row = chunk * 8 + rsub;
            gload16(gA + (size_t)row * 256 + 128 + srcsw, lds + LA1 + chunk * 1024);
            gload16(gB + (size_t)row * 256 + 128 + srcsw, lds + LB1 + chunk * 1024);
        }
        if (w == 0) gload16(En + (size_t)bi * TB + (size_t)l * 4, lds + LEA);
        if (w == 1) gload16(En + (size_t)bj * TB + (size_t)l * 4, lds + LEB);

        while (true) {
            // ---- B1: wait own S0 loads done (S1 + En stay in flight)
            if (w < 2) asm volatile("s_waitcnt vmcnt(5)" ::: "memory");
            else       asm volatile("s_waitcnt vmcnt(4)" ::: "memory");
            SCHEDB();
            __builtin_amdgcn_s_barrier();
            SCHEDB();

            f32x4 acc[4][4];
            const f32x4 zero4 = {0.f, 0.f, 0.f, 0.f};

            // ---- GEMM half 0 (kk=0 peeled with zero C)
            __builtin_amdgcn_s_setprio(1);
#pragma unroll
            for (int kk = 0; kk < 2; ++kk) {
                const int soff = ((kk * 4 + kq) ^ swz) << 4;
                half8 bf[4];
#pragma unroll
                for (int j = 0; j < 4; ++j)
                    bf[j] = *reinterpret_cast<const half8*>(lds + LB0 + (wcol + j * 16 + lr) * 128 + soff);
#pragma unroll
                for (int i = 0; i < 4; ++i) {
                    half8 af = *reinterpret_cast<const half8*>(lds + LA0 + (wrow + i * 16 + lr) * 128 + soff);
#pragma unroll
                    for (int j = 0; j < 4; ++j)
                        acc[i][j] = __builtin_amdgcn_mfma_f32_16x16x32_f16(
                            af, bf[j], (kk == 0) ? zero4 : acc[i][j], 0, 0, 0);
                }
            }
            __builtin_amdgcn_s_setprio(0);

            // ---- B2: all waves done reading buf0 -> safe to restage it
            asm volatile("" ::: "memory");
            __builtin_amdgcn_s_barrier();
            SCHEDB();

            // ---- issue S0' (half0 of next tile); hides under GEMM1+epilogue
            const int itn = it + GRID;
            const bool more = (itn < ntiles);
            int bin = bi, bjn = bj;
            const char* gAn = gA;
            const char* gBn = gB;
            if (more) {
                decode_tile(itn, T, bin, bjn);
                gAn = (const char*)Z16 + (size_t)bin * (TB * TD * 2);
                gBn = (const char*)Z16 + (size_t)bjn * (TB * TD * 2);
#pragma unroll
                for (int q = 0; q < 2; ++q) {
                    const int chunk = w * 2 + q;
                    const int row = chunk * 8 + rsub;
                    gload16(gAn + (size_t)row * 256 + srcsw, lds + LA0 + chunk * 1024);
                    gload16(gBn + (size_t)row * 256 + srcsw, lds + LB0 + chunk * 1024);
                }
            }

            // ---- B3: wait S1 + En done (S0' stays in flight)
            if (more) asm volatile("s_waitcnt vmcnt(4)" ::: "memory");
            else      asm volatile("s_waitcnt vmcnt(0)" ::: "memory");
            SCHEDB();
            __builtin_amdgcn_s_barrier();
            SCHEDB();

            // ---- GEMM half 1
            __builtin_amdgcn_s_setprio(1);
#pragma unroll
            for (int kk = 0; kk < 2; ++kk) {
                const int soff = ((kk * 4 + kq) ^ swz) << 4;
                half8 bf[4];
#pragma unroll
                for (int j = 0; j < 4; ++j)
                    bf[j] = *reinterpret_cast<const half8*>(lds + LB1 + (wcol + j * 16 + lr) * 128 + soff);
#pragma unroll
                for (int i = 0; i < 4; ++i) {
                    half8 af = *reinterpret_cast<const half8*>(lds + LA1 + (wrow + i * 16 + lr) * 128 + soff);
#pragma unroll
                    for (int j = 0; j < 4; ++j)
                        acc[i][j] = __builtin_amdgcn_mfma_f32_16x16x32_f16(af, bf[j], acc[i][j], 0, 0, 0);
                }
            }
            __builtin_amdgcn_s_setprio(0);

            // ---- epilogue (BEFORE B4 so En can be read lazily from LDS,
            //      keeping live registers minimal): K = Ei*Ej*exp2(M2C2*dot)
            float s = 0.f;
#pragma unroll
            for (int j = 0; j < 4; ++j) {
                float Ejv = *reinterpret_cast<const float*>(lds + LEB + (wcol + j * 16 + lr) * 4);
                float sj0 = 0.f, sj1 = 0.f;
#pragma unroll
                for (int i = 0; i < 4; ++i) {
                    f32x4 Eiv = *reinterpret_cast<const f32x4*>(lds + LEA + (wrow + i * 16 + kq * 4) * 4);
#pragma unroll
                    for (int r = 0; r < 4; ++r) {
                        float e = EXP2F(M2C2f * acc[i][j][r]);
                        if (r & 1) sj1 = fmaf(Eiv[r], e, sj1);
                        else       sj0 = fmaf(Eiv[r], e, sj0);
                    }
                }
                s = fmaf(Ejv, sj0 + sj1, s);
            }

            // ---- B4: all LDS reads (buf1 + En) complete -> safe to restage
            asm volatile("s_waitcnt lgkmcnt(0)" ::: "memory");
            SCHEDB();
            __builtin_amdgcn_s_barrier();
            SCHEDB();

            // ---- issue S1' + En' of next tile; latency covered by the
            //      reduce below + next tile's B1/GEMM0 before B3 consumes it
            if (more) {
#pragma unroll
                for (int q = 0; q < 2; ++q) {
                    const int chunk = w * 2 + q;
                    const int row = chunk * 8 + rsub;
                    gload16(gAn + (size_t)row * 256 + 128 + srcsw, lds + LA1 + chunk * 1024);
                    gload16(gBn + (size_t)row * 256 + 128 + srcsw, lds + LB1 + chunk * 1024);
                }
                if (w == 0) gload16(En + (size_t)bin * TB + (size_t)l * 4, lds + LEA);
                if (w == 1) gload16(En + (size_t)bjn * TB + (size_t)l * 4, lds + LEB);
            }

            // ---- wave reduce -> running double accumulator
#pragma unroll
            for (int off = 32; off > 0; off >>= 1) s += __shfl_down(s, off, 64);
            {
                double wa = (bi * TB < n) ? (1.0 / (double)n) : (-1.0 / (double)m);
                double wb = (bj * TB < n) ? (1.0 / (double)n) : (-1.0 / (double)m);
                double wgt = wa * wb * ((bi == bj) ? 1.0 : 2.0);
                acc_d += wgt * (double)s;   // lane 0 holds the wave sum
            }

            if (!more) break;
            it = itn; bi = bin; bj = bjn;
        }
    }

    // one store per wave for the whole kernel
    if (l == 0) partials[(size_t)blockIdx.x * 16 + w] = acc_d;
}

// ---------------------------------------------------------------------------
// Fallback fp32 path (round-1, proven): used only if ws/shape unsuitable
// ---------------------------------------------------------------------------
__global__ __launch_bounds__(256) void norms_kernel(const float* __restrict__ X,
                                                    const float* __restrict__ Y,
                                                    int n, int tot,
                                                    float* __restrict__ norms) {
    int r = blockIdx.x * 256 + threadIdx.x;
    if (r >= tot) return;
    const float* row = (r < n) ? (X + (size_t)r * TD) : (Y + (size_t)(r - n) * TD);
    float s = 0.f;
#pragma unroll
    for (int k = 0; k < TD; k += 4) {
        float4 v = *reinterpret_cast<const float4*>(row + k);
        s = fmaf(v.x, v.x, s); s = fmaf(v.y, v.y, s);
        s = fmaf(v.z, v.z, s); s = fmaf(v.w, v.w, s);
    }
    norms[r] = s;
}

__global__ __launch_bounds__(256, 2) void mmd_tile_kernel(const float* __restrict__ X,
                                                          const float* __restrict__ Y,
                                                          const float* __restrict__ norms,
                                                          double* __restrict__ partials,
                                                          int n, int m, int T) {
    __shared__ float sA[TD][BT];
    __shared__ float sB[TD][BT];
    __shared__ float sredf[4];

    const int t = blockIdx.x;
    int bi, bj;
    decode_tile(t, T, bi, bj);

    const int tid = threadIdx.x;
    {
        const int row = tid & 63;
        const int qb  = tid >> 6;
        const int ra = bi * BT + row;
        const int rb = bj * BT + row;
        const float* Arow = (ra < n) ? (X + (size_t)ra * TD) : (Y + (size_t)(ra - n) * TD);
        const float* Brow = (rb < n) ? (X + (size_t)rb * TD) : (Y + (size_t)(rb - n) * TD);
#pragma unroll
        for (int i = 0; i < 8; ++i) {
            const int q = qb + 4 * i;
            float4 va = *reinterpret_cast<const float4*>(Arow + 4 * q);
            sA[4 * q + 0][row] = va.x; sA[4 * q + 1][row] = va.y;
            sA[4 * q + 2][row] = va.z; sA[4 * q + 3][row] = va.w;
            float4 vb = *reinterpret_cast<const float4*>(Brow + 4 * q);
            sB[4 * q + 0][row] = vb.x; sB[4 * q + 1][row] = vb.y;
            sB[4 * q + 2][row] = vb.z; sB[4 * q + 3][row] = vb.w;
        }
    }
    __syncthreads();

    const int tx = tid & 15;
    const int ty = tid >> 4;
    float acc[4][4];
#pragma unroll
    for (int i = 0; i < 4; ++i)
#pragma unroll
        for (int j = 0; j < 4; ++j) acc[i][j] = 0.f;

#pragma unroll 16
    for (int k = 0; k < TD; ++k) {
        float4 a = *reinterpret_cast<const float4*>(&sA[k][ty * 4]);
        float4 b = *reinterpret_cast<const float4*>(&sB[k][tx * 4]);
        const float av[4] = {a.x, a.y, a.z, a.w};
        const float bv[4] = {b.x, b.y, b.z, b.w};
#pragma unroll
        for (int i = 0; i < 4; ++i)
#pragma unroll
            for (int j = 0; j < 4; ++j)
                acc[i][j] = fmaf(av[i], bv[j], acc[i][j]);
    }

    float nA[4], nB[4];
#pragma unroll
    for (int i = 0; i < 4; ++i) nA[i] = norms[bi * BT + ty * 4 + i];
#pragma unroll
    for (int j = 0; j < 4; ++j) nB[j] = norms[bj * BT + tx * 4 + j];

    const float cexp = -0.005f;
    float s = 0.f;
#pragma unroll
    for (int i = 0; i < 4; ++i)
#pragma unroll
        for (int j = 0; j < 4; ++j) {
            float d2 = fmaxf(nA[i] + nB[j] - 2.f * acc[i][j], 0.f);
            s += __expf(d2 * cexp);
        }

#pragma unroll
    for (int off = 32; off > 0; off >>= 1) s += __shfl_down(s, off, 64);
    if ((tid & 63) == 0) sredf[tid >> 6] = s;
    __syncthreads();
    if (tid == 0) {
        double wa = (bi * BT < n) ? (1.0 / (double)n) : (-1.0 / (double)m);
        double wb = (bj * BT < n) ? (1.0 / (double)n) : (-1.0 / (double)m);
        double wgt = wa * wb * ((bi == bj) ? 1.0 : 2.0);
        partials[t] = wgt * (double)(sredf[0] + sredf[1] + sredf[2] + sredf[3]);
    }
}

// ---------------------------------------------------------------------------
__global__ __launch_bounds__(256) void reduce_kernel(const double* __restrict__ partials,
                                                     int npart,
                                                     float* __restrict__ out) {
    __shared__ double sd[256];
    double s = 0.0;
    for (int i = threadIdx.x; i < npart; i += 256) s += partials[i];
    sd[threadIdx.x] = s;
    __syncthreads();
    for (int off = 128; off > 0; off >>= 1) {
        if ((int)threadIdx.x < off) sd[threadIdx.x] += sd[threadIdx.x + off];
        __syncthreads();
    }
    if (threadIdx.x == 0) out[0] = (float)sd[0];
}

// ---------------------------------------------------------------------------
extern "C" void kernel_launch(void* const* d_in, const int* in_sizes, int n_in,
                              void* d_out, int out_size, void* d_ws, size_t ws_size,
                              hipStream_t stream) {
    const float* X = (const float*)d_in[0];
    const float* Y = (const float*)d_in[1];
    float* out = (float*)d_out;

    const int n = in_sizes[0] / TD;
    const int m = in_sizes[1] / TD;
    const int tot = n + m;

    // fp16-MFMA path workspace: Z16 + En + per-wave partials
    const size_t z16_bytes = (size_t)tot * TD * 2;
    const size_t en_off    = (z16_bytes + 255) & ~(size_t)255;
    const size_t en_bytes  = (size_t)tot * 4;
    const size_t part_off  = ((en_off + en_bytes) + 255) & ~(size_t)255;
    const int Tm = tot / TB;
    const int npart_m = Tm * (Tm + 1) / 2;
    const int grid = (npart_m < GRID) ? npart_m : GRID;
    const int nred = grid * 16;
    const size_t needed = part_off + (size_t)nred * 8;

    if (ws_size >= needed && (tot % TB) == 0 && (n % TB) == 0) {
        _Float16* Z16 = (_Float16*)d_ws;
        float* En = (float*)((char*)d_ws + en_off);
        double* partials = (double*)((char*)d_ws + part_off);
        cvt_norms_kernel<<<(tot + 3) / 4, 256, 0, stream>>>(X, Y, n, tot, Z16, En);
        mmd_pipe_kernel<<<grid, 1024, 0, stream>>>(Z16, En, partials, n, m, Tm, npart_m);
        reduce_kernel<<<1, 256, 0, stream>>>(partials, nred, out);
    } else {
        const int T = tot / BT;
        const int npart = T * (T + 1) / 2;
        float* norms = (float*)d_ws;
        double* partials = (double*)((char*)d_ws + (((size_t)tot * 4 + 255) & ~(size_t)255));
        norms_kernel<<<(tot + 255) / 256, 256, 0, stream>>>(X, Y, n, tot, norms);
        mmd_tile_kernel<<<npart, 256, 0, stream>>>(X, Y, norms, partials, n, m, T);
        reduce_kernel<<<1, 256, 0, stream>>>(partials, npart, out);
    }
}

// Round 8
// 96.789 us; speedup vs baseline: 1.0469x; 1.0469x over previous
//
#include <hip/hip_runtime.h>
#include <math.h>

#define TD 128    // feature dimension
#define BT 64     // fallback tile rows
#define TILE 128  // mfma tile rows per block tile
#define GRIDB 1024 // persistent blocks, 4 per CU
#define NXCD 8

typedef _Float16 half8 __attribute__((ext_vector_type(8)));
typedef _Float16 half2v __attribute__((ext_vector_type(2)));
typedef float f32x4 __attribute__((ext_vector_type(4)));

// K = exp(-d2/(2*10^2)) = 2^(C2*d2);  C2 = -1/(200*ln2)
#define C2f   (-0.0072134752044448f)
#define M2C2f (0.0144269504088896f)   /* -2*C2 */

#if __has_builtin(__builtin_amdgcn_exp2f)
#define EXP2F(x) __builtin_amdgcn_exp2f(x)
#else
#define EXP2F(x) exp2f(x)
#endif

// LDS layout (bytes): 4 quarter-K panels [128 rows][32 fp16 = 64B] + En (1KB)
#define LA0 0
#define LA1 8192
#define LB0 16384
#define LB1 24576
#define LEA 32768          // EnA 512B, EnB at +512
#define LDS_TOT 33792

#define SCHEDB() __builtin_amdgcn_sched_barrier(0)

__device__ __forceinline__ void gload16(const void* g, void* l) {
    __builtin_amdgcn_global_load_lds(
        (const __attribute__((address_space(1))) void*)g,
        (__attribute__((address_space(3))) void*)l, 16, 0, 0);
}

__device__ __forceinline__ void decode_tile(int t, int T, int& bi, int& bj) {
    double bguess = (2.0 * T + 1.0 -
                     sqrt((2.0 * T + 1.0) * (2.0 * T + 1.0) - 8.0 * (double)t)) * 0.5;
    int b = (int)bguess;
    if (b < 0) b = 0;
    if (b > T - 1) b = T - 1;
    while ((b + 1) * T - ((b + 1) * b) / 2 <= t) ++b;
    while (b * T - (b * (b - 1)) / 2 > t) --b;
    bi = b;
    bj = b + (t - (b * T - (b * (b - 1)) / 2));
}

// ---------------------------------------------------------------------------
// Prologue: Z -> fp16 + En[r] = exp2(C2*||f16(z_r)||^2)
// ---------------------------------------------------------------------------
__global__ __launch_bounds__(256) void cvt_norms_kernel(const float* __restrict__ X,
                                                        const float* __restrict__ Y,
                                                        int n, int tot,
                                                        _Float16* __restrict__ Z16,
                                                        float* __restrict__ En) {
    const int wid  = (blockIdx.x * 256 + threadIdx.x) >> 6;
    const int lane = threadIdx.x & 63;
    if (wid >= tot) return;
    const float* row = (wid < n) ? (X + (size_t)wid * TD) : (Y + (size_t)(wid - n) * TD);
    float2 v = *reinterpret_cast<const float2*>(row + lane * 2);
    _Float16 hx = (_Float16)v.x;
    _Float16 hy = (_Float16)v.y;
    half2v h2 = {hx, hy};
    *reinterpret_cast<half2v*>(Z16 + (size_t)wid * TD + lane * 2) = h2;
    float fx = (float)hx, fy = (float)hy;
    float s = fmaf(fx, fx, fy * fy);
#pragma unroll
    for (int off = 32; off > 0; off >>= 1) s += __shfl_down(s, off, 64);
    if (lane == 0) En[wid] = EXP2F(C2f * s);
}

// ---------------------------------------------------------------------------
// Main: 256 threads / 4 waves, 33KB LDS -> 4 blocks/CU -> 4 waves/SIMD
// (cross-block overlap replaces the failed 16-wave single-block design;
//  r6/r7 lesson: 1024-thr blocks force a 64-VGPR compiler target -> spills).
// 128x128 triangular tiles, wave = 64x64 (acc 64 VGPR).  K=128 in four
// 32-quarters, ping-pong LDS buffers, counted vmcnt, stage-under-compute.
// XCD-partitioned persistent tile ranges for L2 locality.
// Fragment slot swizzle kq^((lr>>1)&3): 2-way LDS banking (free).
// ---------------------------------------------------------------------------
__global__ __launch_bounds__(256, 4)
void mmd_pipe_kernel(const _Float16* __restrict__ Z16,
                     const float* __restrict__ En,
                     double* __restrict__ partials,
                     int n, int m, int T, int ntiles) {
    __shared__ char lds[LDS_TOT];

    const int tid = threadIdx.x;
    const int l = tid & 63;
    const int w = tid >> 6;            // wave 0..3
    const int lr = l & 15;             // row/col within 16-block
    const int kq = l >> 4;             // k-quarter slot within 64B row
    const int soff = ((kq ^ ((lr >> 1) & 3)) << 4);  // swizzled frag byte off
    const int wrow = (w >> 1) * 64;    // 0 or 64
    const int wcol = (w & 1) * 64;     // 0 or 64

    // staging: chunk = 1KB = 16 rows x 64B; wave w owns chunks {2w, 2w+1}
    const int g16 = (((l & 3) ^ ((l >> 3) & 3)) << 4);  // inverse-swizzled src
    const int r0 = (w * 2) * 16 + (l >> 2);
    const int r1 = (w * 2 + 1) * 16 + (l >> 2);
    const int lc0 = (w * 2) * 1024;
    const int lc1 = (w * 2 + 1) * 1024;

#define STAGE_Q(gAp, gBp, Q) do { \
        gload16((gAp) + (size_t)r0 * 256 + (Q) * 64 + g16, lds + LApar_ + lc0); \
        gload16((gAp) + (size_t)r1 * 256 + (Q) * 64 + g16, lds + LApar_ + lc1); \
        gload16((gBp) + (size_t)r0 * 256 + (Q) * 64 + g16, lds + LBpar_ + lc0); \
        gload16((gBp) + (size_t)r1 * 256 + (Q) * 64 + g16, lds + LBpar_ + lc1); \
    } while (0)

    const f32x4 zero4 = {0.f, 0.f, 0.f, 0.f};
    double acc_d = 0.0;

    // XCD-partitioned persistent range (blockIdx%8 -> XCD round-robin)
    const int per_xcd = (ntiles + NXCD - 1) / NXCD;
    const int xcd = blockIdx.x & (NXCD - 1);
    const int bidx = blockIdx.x >> 3;
    const int stride = GRIDB / NXCD;   // 128
    int it = xcd * per_xcd + bidx;
    int tend = xcd * per_xcd + per_xcd;
    if (tend > ntiles) tend = ntiles;

    if (it < tend) {
        int bi, bj;
        decode_tile(it, T, bi, bj);
        const char* gA = (const char*)Z16 + (size_t)bi * (TILE * TD * 2);
        const char* gB = (const char*)Z16 + (size_t)bj * (TILE * TD * 2);

        // prologue: stage q0 -> buf0, q1 -> buf1, En (one per-lane-split load)
        { const int LApar_ = LA0, LBpar_ = LB0; STAGE_Q(gA, gB, 0); }
        { const int LApar_ = LA1, LBpar_ = LB1; STAGE_Q(gA, gB, 1); }
        if (w == 0) {
            const float* eb = (l < 32) ? (En + (size_t)bi * TILE + (size_t)l * 4)
                                       : (En + (size_t)bj * TILE + (size_t)(l - 32) * 4);
            gload16(eb, lds + LEA);
        }

        while (true) {
            f32x4 acc[4][4];

#define GEMM_PH(LAx, LBx, ZERO) do { \
            half8 bf[4]; \
            _Pragma("unroll") \
            for (int j = 0; j < 4; ++j) \
                bf[j] = *reinterpret_cast<const half8*>(lds + (LAx##_UNUSED, LBx) + (wcol + j * 16 + lr) * 64 + soff); \
            __builtin_amdgcn_s_setprio(1); \
            _Pragma("unroll") \
            for (int i = 0; i < 4; ++i) { \
                half8 af = *reinterpret_cast<const half8*>(lds + (LAx) + (wrow + i * 16 + lr) * 64 + soff); \
                _Pragma("unroll") \
                for (int j = 0; j < 4; ++j) \
                    acc[i][j] = __builtin_amdgcn_mfma_f32_16x16x32_f16( \
                        af, bf[j], (ZERO) ? zero4 : acc[i][j], 0, 0, 0); \
            } \
            __builtin_amdgcn_s_setprio(0); \
        } while (0)
#define LA0_UNUSED 0
#define LA1_UNUSED 0

            // ---- P0: quarter 0 (buf0), then stage q2 -> buf0
            if (w == 0) asm volatile("s_waitcnt vmcnt(5)" ::: "memory");
            else        asm volatile("s_waitcnt vmcnt(4)" ::: "memory");
            SCHEDB(); __builtin_amdgcn_s_barrier(); SCHEDB();
            GEMM_PH(LA0, LB0, true);
            asm volatile("s_waitcnt lgkmcnt(0)" ::: "memory");
            __builtin_amdgcn_s_barrier(); SCHEDB();
            { const int LApar_ = LA0, LBpar_ = LB0; STAGE_Q(gA, gB, 2); }

            // ---- P1: quarter 1 (buf1), then stage q3 -> buf1
            if (w == 0) asm volatile("s_waitcnt vmcnt(5)" ::: "memory");
            else        asm volatile("s_waitcnt vmcnt(4)" ::: "memory");
            SCHEDB(); __builtin_amdgcn_s_barrier(); SCHEDB();
            GEMM_PH(LA1, LB1, false);
            asm volatile("s_waitcnt lgkmcnt(0)" ::: "memory");
            __builtin_amdgcn_s_barrier(); SCHEDB();
            { const int LApar_ = LA1, LBpar_ = LB1; STAGE_Q(gA, gB, 3); }

            // ---- P2: quarter 2 (buf0), then stage q0 of NEXT tile -> buf0
            asm volatile("s_waitcnt vmcnt(4)" ::: "memory");
            SCHEDB(); __builtin_amdgcn_s_barrier(); SCHEDB();
            GEMM_PH(LA0, LB0, false);
            asm volatile("s_waitcnt lgkmcnt(0)" ::: "memory");
            __builtin_amdgcn_s_barrier(); SCHEDB();
            const int itn = it + stride;
            const bool more = (itn < tend);
            int bin = bi, bjn = bj;
            const char* gAn = gA;
            const char* gBn = gB;
            if (more) {
                decode_tile(itn, T, bin, bjn);
                gAn = (const char*)Z16 + (size_t)bin * (TILE * TD * 2);
                gBn = (const char*)Z16 + (size_t)bjn * (TILE * TD * 2);
                const int LApar_ = LA0, LBpar_ = LB0;
                STAGE_Q(gAn, gBn, 0);
            }

            // ---- P3: quarter 3 (buf1), then stage q1 of next tile -> buf1
            if (more) asm volatile("s_waitcnt vmcnt(4)" ::: "memory");
            else      asm volatile("s_waitcnt vmcnt(0)" ::: "memory");
            SCHEDB(); __builtin_amdgcn_s_barrier(); SCHEDB();
            GEMM_PH(LA1, LB1, false);
            asm volatile("s_waitcnt lgkmcnt(0)" ::: "memory");
            __builtin_amdgcn_s_barrier(); SCHEDB();
            if (more) {
                const int LApar_ = LA1, LBpar_ = LB1;
                STAGE_Q(gAn, gBn, 1);
            }

            // ---- epilogue: K = Ei * Ej * exp2(M2C2 * dot), En from LDS
            float s = 0.f;
#pragma unroll
            for (int j = 0; j < 4; ++j) {
                float Ejv = *reinterpret_cast<const float*>(lds + LEA + 512 + (wcol + j * 16 + lr) * 4);
                float sj0 = 0.f, sj1 = 0.f;
#pragma unroll
                for (int i = 0; i < 4; ++i) {
                    f32x4 Eiv = *reinterpret_cast<const f32x4*>(lds + LEA + (wrow + i * 16 + kq * 4) * 4);
#pragma unroll
                    for (int r = 0; r < 4; ++r) {
                        float e = EXP2F(M2C2f * acc[i][j][r]);
                        if (r & 1) sj1 = fmaf(Eiv[r], e, sj1);
                        else       sj0 = fmaf(Eiv[r], e, sj0);
                    }
                }
                s = fmaf(Ejv, sj0 + sj1, s);
            }

            // ---- release En, then issue En of next tile
            asm volatile("s_waitcnt lgkmcnt(0)" ::: "memory");
            SCHEDB(); __builtin_amdgcn_s_barrier(); SCHEDB();
            if (more && w == 0) {
                const float* eb = (l < 32) ? (En + (size_t)bin * TILE + (size_t)l * 4)
                                           : (En + (size_t)bjn * TILE + (size_t)(l - 32) * 4);
                gload16(eb, lds + LEA);
            }

            // ---- wave reduce -> running double accumulator
#pragma unroll
            for (int off = 32; off > 0; off >>= 1) s += __shfl_down(s, off, 64);
            {
                double wa = (bi * TILE < n) ? (1.0 / (double)n) : (-1.0 / (double)m);
                double wb = (bj * TILE < n) ? (1.0 / (double)n) : (-1.0 / (double)m);
                double wgt = wa * wb * ((bi == bj) ? 1.0 : 2.0);
                acc_d += wgt * (double)s;   // lane 0 holds the wave sum
            }

            if (!more) break;
            it = itn; bi = bin; bj = bjn; gA = gAn; gB = gBn;
        }
    }

    if (l == 0) partials[(size_t)blockIdx.x * 4 + w] = acc_d;
}

// ---------------------------------------------------------------------------
// Fallback fp32 path (round-1, proven): used only if ws/shape unsuitable
// ---------------------------------------------------------------------------
__global__ __launch_bounds__(256) void norms_kernel(const float* __restrict__ X,
                                                    const float* __restrict__ Y,
                                                    int n, int tot,
                                                    float* __restrict__ norms) {
    int r = blockIdx.x * 256 + threadIdx.x;
    if (r >= tot) return;
    const float* row = (r < n) ? (X + (size_t)r * TD) : (Y + (size_t)(r - n) * TD);
    float s = 0.f;
#pragma unroll
    for (int k = 0; k < TD; k += 4) {
        float4 v = *reinterpret_cast<const float4*>(row + k);
        s = fmaf(v.x, v.x, s); s = fmaf(v.y, v.y, s);
        s = fmaf(v.z, v.z, s); s = fmaf(v.w, v.w, s);
    }
    norms[r] = s;
}

__global__ __launch_bounds__(256, 2) void mmd_tile_kernel(const float* __restrict__ X,
                                                          const float* __restrict__ Y,
                                                          const float* __restrict__ norms,
                                                          double* __restrict__ partials,
                                                          int n, int m, int T) {
    __shared__ float sA[TD][BT];
    __shared__ float sB[TD][BT];
    __shared__ float sredf[4];

    const int t = blockIdx.x;
    int bi, bj;
    decode_tile(t, T, bi, bj);

    const int tid = threadIdx.x;
    {
        const int row = tid & 63;
        const int qb  = tid >> 6;
        const int ra = bi * BT + row;
        const int rb = bj * BT + row;
        const float* Arow = (ra < n) ? (X + (size_t)ra * TD) : (Y + (size_t)(ra - n) * TD);
        const float* Brow = (rb < n) ? (X + (size_t)rb * TD) : (Y + (size_t)(rb - n) * TD);
#pragma unroll
        for (int i = 0; i < 8; ++i) {
            const int q = qb + 4 * i;
            float4 va = *reinterpret_cast<const float4*>(Arow + 4 * q);
            sA[4 * q + 0][row] = va.x; sA[4 * q + 1][row] = va.y;
            sA[4 * q + 2][row] = va.z; sA[4 * q + 3][row] = va.w;
            float4 vb = *reinterpret_cast<const float4*>(Brow + 4 * q);
            sB[4 * q + 0][row] = vb.x; sB[4 * q + 1][row] = vb.y;
            sB[4 * q + 2][row] = vb.z; sB[4 * q + 3][row] = vb.w;
        }
    }
    __syncthreads();

    const int tx = tid & 15;
    const int ty = tid >> 4;
    float acc[4][4];
#pragma unroll
    for (int i = 0; i < 4; ++i)
#pragma unroll
        for (int j = 0; j < 4; ++j) acc[i][j] = 0.f;

#pragma unroll 16
    for (int k = 0; k < TD; ++k) {
        float4 a = *reinterpret_cast<const float4*>(&sA[k][ty * 4]);
        float4 b = *reinterpret_cast<const float4*>(&sB[k][tx * 4]);
        const float av[4] = {a.x, a.y, a.z, a.w};
        const float bv[4] = {b.x, b.y, b.z, b.w};
#pragma unroll
        for (int i = 0; i < 4; ++i)
#pragma unroll
            for (int j = 0; j < 4; ++j)
                acc[i][j] = fmaf(av[i], bv[j], acc[i][j]);
    }

    float nA[4], nB[4];
#pragma unroll
    for (int i = 0; i < 4; ++i) nA[i] = norms[bi * BT + ty * 4 + i];
#pragma unroll
    for (int j = 0; j < 4; ++j) nB[j] = norms[bj * BT + tx * 4 + j];

    const float cexp = -0.005f;
    float s = 0.f;
#pragma unroll
    for (int i = 0; i < 4; ++i)
#pragma unroll
        for (int j = 0; j < 4; ++j) {
            float d2 = fmaxf(nA[i] + nB[j] - 2.f * acc[i][j], 0.f);
            s += __expf(d2 * cexp);
        }

#pragma unroll
    for (int off = 32; off > 0; off >>= 1) s += __shfl_down(s, off, 64);
    if ((tid & 63) == 0) sredf[tid >> 6] = s;
    __syncthreads();
    if (tid == 0) {
        double wa = (bi * BT < n) ? (1.0 / (double)n) : (-1.0 / (double)m);
        double wb = (bj * BT < n) ? (1.0 / (double)n) : (-1.0 / (double)m);
        double wgt = wa * wb * ((bi == bj) ? 1.0 : 2.0);
        partials[t] = wgt * (double)(sredf[0] + sredf[1] + sredf[2] + sredf[3]);
    }
}

// ---------------------------------------------------------------------------
__global__ __launch_bounds__(256) void reduce_kernel(const double* __restrict__ partials,
                                                     int npart,
                                                     float* __restrict__ out) {
    __shared__ double sd[256];
    double s = 0.0;
    for (int i = threadIdx.x; i < npart; i += 256) s += partials[i];
    sd[threadIdx.x] = s;
    __syncthreads();
    for (int off = 128; off > 0; off >>= 1) {
        if ((int)threadIdx.x < off) sd[threadIdx.x] += sd[threadIdx.x + off];
        __syncthreads();
    }
    if (threadIdx.x == 0) out[0] = (float)sd[0];
}

// ---------------------------------------------------------------------------
extern "C" void kernel_launch(void* const* d_in, const int* in_sizes, int n_in,
                              void* d_out, int out_size, void* d_ws, size_t ws_size,
                              hipStream_t stream) {
    const float* X = (const float*)d_in[0];
    const float* Y = (const float*)d_in[1];
    float* out = (float*)d_out;

    const int n = in_sizes[0] / TD;
    const int m = in_sizes[1] / TD;
    const int tot = n + m;

    // fp16-MFMA path workspace: Z16 + En + per-(block,wave) partials
    const size_t z16_bytes = (size_t)tot * TD * 2;
    const size_t en_off    = (z16_bytes + 255) & ~(size_t)255;
    const size_t en_bytes  = (size_t)tot * 4;
    const size_t part_off  = ((en_off + en_bytes) + 255) & ~(size_t)255;
    const int Tm = tot / TILE;
    const int npart_m = Tm * (Tm + 1) / 2;
    const int nred = GRIDB * 4;
    const size_t needed = part_off + (size_t)nred * 8;

    if (ws_size >= needed && (tot % TILE) == 0 && (n % TILE) == 0) {
        _Float16* Z16 = (_Float16*)d_ws;
        float* En = (float*)((char*)d_ws + en_off);
        double* partials = (double*)((char*)d_ws + part_off);
        cvt_norms_kernel<<<(tot + 3) / 4, 256, 0, stream>>>(X, Y, n, tot, Z16, En);
        mmd_pipe_kernel<<<GRIDB, 256, 0, stream>>>(Z16, En, partials, n, m, Tm, npart_m);
        reduce_kernel<<<1, 256, 0, stream>>>(partials, nred, out);
    } else {
        const int T = tot / BT;
        const int npart = T * (T + 1) / 2;
        float* norms = (float*)d_ws;
        double* partials = (double*)((char*)d_ws + (((size_t)tot * 4 + 255) & ~(size_t)255));
        norms_kernel<<<(tot + 255) / 256, 256, 0, stream>>>(X, Y, n, tot, norms);
        mmd_tile_kernel<<<npart, 256, 0, stream>>>(X, Y, norms, partials, n, m, T);
        reduce_kernel<<<1, 256, 0, stream>>>(partials, npart, out);
    }
}

// Round 9
// 69.040 us; speedup vs baseline: 1.4677x; 1.4019x over previous
//
#include <hip/hip_runtime.h>
#include <math.h>

#define TD 128     // feature dimension
#define BT 64      // fallback tile rows
#define TILE 256   // tile rows per block tile
#define GRIDB 512  // persistent blocks, 2 per CU
#define NXCD 8

typedef _Float16 half8 __attribute__((ext_vector_type(8)));
typedef _Float16 half2v __attribute__((ext_vector_type(2)));
typedef float f32x4 __attribute__((ext_vector_type(4)));

// K = exp(-d2/(2*10^2)) = 2^(C2*d2);  C2 = -1/(200*ln2)
#define C2f   (-0.0072134752044448f)
#define M2C2f (0.0144269504088896f)   /* -2*C2 */

#if __has_builtin(__builtin_amdgcn_exp2f)
#define EXP2F(x) __builtin_amdgcn_exp2f(x)
#else
#define EXP2F(x) exp2f(x)
#endif

// LDS layout (bytes): 4 quarter-K panels [256 rows][32 fp16 = 64B] = 16KB each
// A0 @0, A1 @16K, B0 @32K, B1 @48K, EnA @64K (1KB), EnB @65K (1KB)
#define LA0 0
#define LA1 16384
#define LB0 32768
#define LB1 49152
#define LEA 65536
#define LEB 66560
#define LDS_TOT 67584

#define SCHEDB() __builtin_amdgcn_sched_barrier(0)

__device__ __forceinline__ void gload16(const void* g, void* l) {
    __builtin_amdgcn_global_load_lds(
        (const __attribute__((address_space(1))) void*)g,
        (__attribute__((address_space(3))) void*)l, 16, 0, 0);
}

__device__ __forceinline__ void decode_tile(int t, int T, int& bi, int& bj) {
    double bguess = (2.0 * T + 1.0 -
                     sqrt((2.0 * T + 1.0) * (2.0 * T + 1.0) - 8.0 * (double)t)) * 0.5;
    int b = (int)bguess;
    if (b < 0) b = 0;
    if (b > T - 1) b = T - 1;
    while ((b + 1) * T - ((b + 1) * b) / 2 <= t) ++b;
    while (b * T - (b * (b - 1)) / 2 > t) --b;
    bi = b;
    bj = b + (t - (b * T - (b * (b - 1)) / 2));
}

// ---------------------------------------------------------------------------
// Prologue: Z -> fp16 + En[r] = exp2(C2*||f16(z_r)||^2)
// ---------------------------------------------------------------------------
__global__ __launch_bounds__(256) void cvt_norms_kernel(const float* __restrict__ X,
                                                        const float* __restrict__ Y,
                                                        int n, int tot,
                                                        _Float16* __restrict__ Z16,
                                                        float* __restrict__ En) {
    const int wid  = (blockIdx.x * 256 + threadIdx.x) >> 6;
    const int lane = threadIdx.x & 63;
    if (wid >= tot) return;
    const float* row = (wid < n) ? (X + (size_t)wid * TD) : (Y + (size_t)(wid - n) * TD);
    float2 v = *reinterpret_cast<const float2*>(row + lane * 2);
    _Float16 hx = (_Float16)v.x;
    _Float16 hy = (_Float16)v.y;
    half2v h2 = {hx, hy};
    *reinterpret_cast<half2v*>(Z16 + (size_t)wid * TD + lane * 2) = h2;
    float fx = (float)hx, fy = (float)hy;
    float s = fmaf(fx, fx, fy * fy);
#pragma unroll
    for (int off = 32; off > 0; off >>= 1) s += __shfl_down(s, off, 64);
    if (lane == 0) En[wid] = EXP2F(C2f * s);
}

// ---------------------------------------------------------------------------
// Main: 512 threads / 8 waves (r5's PROVEN no-spill compile shape:
// __launch_bounds__(512,2) -> 128-VGPR budget; second-arg-4 variants all
// spilled to 64 VGPR in r6/r7/r8).  66KB LDS -> 2 blocks/CU -> 4 waves/SIMD.
// 256x256 triangular tiles, wave = 128x64 (acc[8][4], AGPR-backed).
// K=128 in four 32-quarters, ping-pong buffers, counted vmcnt (never 0
// until last tile), stage-under-compute, XCD-partitioned tile ranges,
// per-wave double accumulator across tiles.
// ---------------------------------------------------------------------------
__global__ __launch_bounds__(512, 2)
void mmd_pipe_kernel(const _Float16* __restrict__ Z16,
                     const float* __restrict__ En,
                     double* __restrict__ partials,
                     int n, int m, int T, int ntiles) {
    __shared__ char lds[LDS_TOT];

    const int tid = threadIdx.x;
    const int l = tid & 63;
    const int w = tid >> 6;            // wave 0..7
    const int lr = l & 15;             // row/col within 16-block
    const int kq = l >> 4;             // k-quarter slot within 64B row
    const int soff = (kq ^ ((lr >> 1) & 3)) << 4;   // swizzled frag byte off
    const int wrow = (w >> 2) * 128;   // 0 or 128
    const int wcol = (w & 3) * 64;     // 0,64,128,192

    // staging: panel quarter = 256 rows x 64B = 16KB = 1024 x 16B lane-loads;
    // thread p handles element16 p and p+512: row = p>>2 (+128), slot = p&3,
    // source slot inverse-swizzled to match the frag-read swizzle.
    const int srow = tid >> 2;                           // 0..127
    const int g16  = ((tid & 3) ^ ((tid >> 3) & 3)) << 4;
    const int ldst = w * 1024;                           // wave-uniform chunk

#define STAGE_Q(gAp, gBp, Q, LAx, LBx) do { \
        gload16((gAp) + (size_t)srow * 256 + (Q) * 64 + g16,         lds + (LAx) + ldst); \
        gload16((gAp) + (size_t)(srow + 128) * 256 + (Q) * 64 + g16, lds + (LAx) + ldst + 8192); \
        gload16((gBp) + (size_t)srow * 256 + (Q) * 64 + g16,         lds + (LBx) + ldst); \
        gload16((gBp) + (size_t)(srow + 128) * 256 + (Q) * 64 + g16, lds + (LBx) + ldst + 8192); \
    } while (0)

#define GEMM_Q(LAx, LBx, ZERO) do { \
        half8 bf[4]; \
        _Pragma("unroll") \
        for (int j = 0; j < 4; ++j) \
            bf[j] = *reinterpret_cast<const half8*>(lds + (LBx) + (wcol + j * 16 + lr) * 64 + soff); \
        __builtin_amdgcn_s_setprio(1); \
        _Pragma("unroll") \
        for (int i = 0; i < 8; ++i) { \
            half8 af = *reinterpret_cast<const half8*>(lds + (LAx) + (wrow + i * 16 + lr) * 64 + soff); \
            _Pragma("unroll") \
            for (int j = 0; j < 4; ++j) \
                acc[i][j] = __builtin_amdgcn_mfma_f32_16x16x32_f16( \
                    af, bf[j], (ZERO) ? zero4 : acc[i][j], 0, 0, 0); \
        } \
        __builtin_amdgcn_s_setprio(0); \
    } while (0)

    const f32x4 zero4 = {0.f, 0.f, 0.f, 0.f};
    double acc_d = 0.0;

    // XCD-partitioned persistent range
    const int per_xcd = (ntiles + NXCD - 1) / NXCD;
    const int xcd = blockIdx.x & (NXCD - 1);
    const int bidx = blockIdx.x >> 3;
    const int stride = GRIDB / NXCD;   // 64
    int it = xcd * per_xcd + bidx;
    int tend = xcd * per_xcd + per_xcd;
    if (tend > ntiles) tend = ntiles;

    if (it < tend) {
        int bi, bj;
        decode_tile(it, T, bi, bj);
        const char* gA = (const char*)Z16 + (size_t)bi * (TILE * TD * 2);
        const char* gB = (const char*)Z16 + (size_t)bj * (TILE * TD * 2);

        // prologue: q0 -> buf0, q1 -> buf1, En (waves 0/1)
        STAGE_Q(gA, gB, 0, LA0, LB0);
        STAGE_Q(gA, gB, 1, LA1, LB1);
        if (w == 0) gload16(En + (size_t)bi * TILE + (size_t)l * 4, lds + LEA);
        if (w == 1) gload16(En + (size_t)bj * TILE + (size_t)l * 4, lds + LEB);

        while (true) {
            f32x4 acc[8][4];

            // ---- P0: quarter 0 (buf0); then stage q2 -> buf0
            if (w < 2) asm volatile("s_waitcnt vmcnt(5)" ::: "memory");
            else       asm volatile("s_waitcnt vmcnt(4)" ::: "memory");
            SCHEDB(); __builtin_amdgcn_s_barrier(); SCHEDB();
            GEMM_Q(LA0, LB0, true);
            asm volatile("s_waitcnt lgkmcnt(0)" ::: "memory");
            __builtin_amdgcn_s_barrier(); SCHEDB();
            STAGE_Q(gA, gB, 2, LA0, LB0);

            // ---- P1: quarter 1 (buf1); then stage q3 -> buf1
            if (w < 2) asm volatile("s_waitcnt vmcnt(5)" ::: "memory");
            else       asm volatile("s_waitcnt vmcnt(4)" ::: "memory");
            SCHEDB(); __builtin_amdgcn_s_barrier(); SCHEDB();
            GEMM_Q(LA1, LB1, false);
            asm volatile("s_waitcnt lgkmcnt(0)" ::: "memory");
            __builtin_amdgcn_s_barrier(); SCHEDB();
            STAGE_Q(gA, gB, 3, LA1, LB1);

            // ---- P2: quarter 2 (buf0); then stage q0 of NEXT tile -> buf0
            asm volatile("s_waitcnt vmcnt(4)" ::: "memory");
            SCHEDB(); __builtin_amdgcn_s_barrier(); SCHEDB();
            GEMM_Q(LA0, LB0, false);
            asm volatile("s_waitcnt lgkmcnt(0)" ::: "memory");
            __builtin_amdgcn_s_barrier(); SCHEDB();
            const int itn = it + stride;
            const bool more = (itn < tend);
            int bin = bi, bjn = bj;
            const char* gAn = gA;
            const char* gBn = gB;
            if (more) {
                decode_tile(itn, T, bin, bjn);
                gAn = (const char*)Z16 + (size_t)bin * (TILE * TD * 2);
                gBn = (const char*)Z16 + (size_t)bjn * (TILE * TD * 2);
                STAGE_Q(gAn, gBn, 0, LA0, LB0);
            }

            // ---- P3: quarter 3 (buf1); then stage q1 of next tile -> buf1
            if (more) asm volatile("s_waitcnt vmcnt(4)" ::: "memory");
            else      asm volatile("s_waitcnt vmcnt(0)" ::: "memory");
            SCHEDB(); __builtin_amdgcn_s_barrier(); SCHEDB();
            GEMM_Q(LA1, LB1, false);
            asm volatile("s_waitcnt lgkmcnt(0)" ::: "memory");
            __builtin_amdgcn_s_barrier(); SCHEDB();
            if (more) STAGE_Q(gAn, gBn, 1, LA1, LB1);

            // ---- epilogue: K = Ei * Ej * exp2(M2C2 * dot), En lazy from LDS
            float s = 0.f;
#pragma unroll
            for (int j = 0; j < 4; ++j) {
                float Ejv = *reinterpret_cast<const float*>(lds + LEB + (wcol + j * 16 + lr) * 4);
                float sj0 = 0.f, sj1 = 0.f;
#pragma unroll
                for (int i = 0; i < 8; ++i) {
                    f32x4 Eiv = *reinterpret_cast<const f32x4*>(lds + LEA + (wrow + i * 16 + kq * 4) * 4);
#pragma unroll
                    for (int r = 0; r < 4; ++r) {
                        float e = EXP2F(M2C2f * acc[i][j][r]);
                        if (r & 1) sj1 = fmaf(Eiv[r], e, sj1);
                        else       sj0 = fmaf(Eiv[r], e, sj0);
                    }
                }
                s = fmaf(Ejv, sj0 + sj1, s);
            }

            // ---- release En buffers, then issue En of next tile
            asm volatile("s_waitcnt lgkmcnt(0)" ::: "memory");
            SCHEDB(); __builtin_amdgcn_s_barrier(); SCHEDB();
            if (more && w == 0) gload16(En + (size_t)bin * TILE + (size_t)l * 4, lds + LEA);
            if (more && w == 1) gload16(En + (size_t)bjn * TILE + (size_t)l * 4, lds + LEB);

            // ---- wave reduce -> running double accumulator
#pragma unroll
            for (int off = 32; off > 0; off >>= 1) s += __shfl_down(s, off, 64);
            {
                double wa = (bi * TILE < n) ? (1.0 / (double)n) : (-1.0 / (double)m);
                double wb = (bj * TILE < n) ? (1.0 / (double)n) : (-1.0 / (double)m);
                double wgt = wa * wb * ((bi == bj) ? 1.0 : 2.0);
                acc_d += wgt * (double)s;   // lane 0 holds the wave sum
            }

            if (!more) break;
            it = itn; bi = bin; bj = bjn; gA = gAn; gB = gBn;
        }
    }

    if (l == 0) partials[(size_t)blockIdx.x * 8 + w] = acc_d;
}

// ---------------------------------------------------------------------------
// Fallback fp32 path (round-1, proven): used only if ws/shape unsuitable
// ---------------------------------------------------------------------------
__global__ __launch_bounds__(256) void norms_kernel(const float* __restrict__ X,
                                                    const float* __restrict__ Y,
                                                    int n, int tot,
                                                    float* __restrict__ norms) {
    int r = blockIdx.x * 256 + threadIdx.x;
    if (r >= tot) return;
    const float* row = (r < n) ? (X + (size_t)r * TD) : (Y + (size_t)(r - n) * TD);
    float s = 0.f;
#pragma unroll
    for (int k = 0; k < TD; k += 4) {
        float4 v = *reinterpret_cast<const float4*>(row + k);
        s = fmaf(v.x, v.x, s); s = fmaf(v.y, v.y, s);
        s = fmaf(v.z, v.z, s); s = fmaf(v.w, v.w, s);
    }
    norms[r] = s;
}

__global__ __launch_bounds__(256, 2) void mmd_tile_kernel(const float* __restrict__ X,
                                                          const float* __restrict__ Y,
                                                          const float* __restrict__ norms,
                                                          double* __restrict__ partials,
                                                          int n, int m, int T) {
    __shared__ float sA[TD][BT];
    __shared__ float sB[TD][BT];
    __shared__ float sredf[4];

    const int t = blockIdx.x;
    int bi, bj;
    decode_tile(t, T, bi, bj);

    const int tid = threadIdx.x;
    {
        const int row = tid & 63;
        const int qb  = tid >> 6;
        const int ra = bi * BT + row;
        const int rb = bj * BT + row;
        const float* Arow = (ra < n) ? (X + (size_t)ra * TD) : (Y + (size_t)(ra - n) * TD);
        const float* Brow = (rb < n) ? (X + (size_t)rb * TD) : (Y + (size_t)(rb - n) * TD);
#pragma unroll
        for (int i = 0; i < 8; ++i) {
            const int q = qb + 4 * i;
            float4 va = *reinterpret_cast<const float4*>(Arow + 4 * q);
            sA[4 * q + 0][row] = va.x; sA[4 * q + 1][row] = va.y;
            sA[4 * q + 2][row] = va.z; sA[4 * q + 3][row] = va.w;
            float4 vb = *reinterpret_cast<const float4*>(Brow + 4 * q);
            sB[4 * q + 0][row] = vb.x; sB[4 * q + 1][row] = vb.y;
            sB[4 * q + 2][row] = vb.z; sB[4 * q + 3][row] = vb.w;
        }
    }
    __syncthreads();

    const int tx = tid & 15;
    const int ty = tid >> 4;
    float acc[4][4];
#pragma unroll
    for (int i = 0; i < 4; ++i)
#pragma unroll
        for (int j = 0; j < 4; ++j) acc[i][j] = 0.f;

#pragma unroll 16
    for (int k = 0; k < TD; ++k) {
        float4 a = *reinterpret_cast<const float4*>(&sA[k][ty * 4]);
        float4 b = *reinterpret_cast<const float4*>(&sB[k][tx * 4]);
        const float av[4] = {a.x, a.y, a.z, a.w};
        const float bv[4] = {b.x, b.y, b.z, b.w};
#pragma unroll
        for (int i = 0; i < 4; ++i)
#pragma unroll
            for (int j = 0; j < 4; ++j)
                acc[i][j] = fmaf(av[i], bv[j], acc[i][j]);
    }

    float nA[4], nB[4];
#pragma unroll
    for (int i = 0; i < 4; ++i) nA[i] = norms[bi * BT + ty * 4 + i];
#pragma unroll
    for (int j = 0; j < 4; ++j) nB[j] = norms[bj * BT + tx * 4 + j];

    const float cexp = -0.005f;
    float s = 0.f;
#pragma unroll
    for (int i = 0; i < 4; ++i)
#pragma unroll
        for (int j = 0; j < 4; ++j) {
            float d2 = fmaxf(nA[i] + nB[j] - 2.f * acc[i][j], 0.f);
            s += __expf(d2 * cexp);
        }

#pragma unroll
    for (int off = 32; off > 0; off >>= 1) s += __shfl_down(s, off, 64);
    if ((tid & 63) == 0) sredf[tid >> 6] = s;
    __syncthreads();
    if (tid == 0) {
        double wa = (bi * BT < n) ? (1.0 / (double)n) : (-1.0 / (double)m);
        double wb = (bj * BT < n) ? (1.0 / (double)n) : (-1.0 / (double)m);
        double wgt = wa * wb * ((bi == bj) ? 1.0 : 2.0);
        partials[t] = wgt * (double)(sredf[0] + sredf[1] + sredf[2] + sredf[3]);
    }
}

// ---------------------------------------------------------------------------
__global__ __launch_bounds__(256) void reduce_kernel(const double* __restrict__ partials,
                                                     int npart,
                                                     float* __restrict__ out) {
    __shared__ double sd[256];
    double s = 0.0;
    for (int i = threadIdx.x; i < npart; i += 256) s += partials[i];
    sd[threadIdx.x] = s;
    __syncthreads();
    for (int off = 128; off > 0; off >>= 1) {
        if ((int)threadIdx.x < off) sd[threadIdx.x] += sd[threadIdx.x + off];
        __syncthreads();
    }
    if (threadIdx.x == 0) out[0] = (float)sd[0];
}

// ---------------------------------------------------------------------------
extern "C" void kernel_launch(void* const* d_in, const int* in_sizes, int n_in,
                              void* d_out, int out_size, void* d_ws, size_t ws_size,
                              hipStream_t stream) {
    const float* X = (const float*)d_in[0];
    const float* Y = (const float*)d_in[1];
    float* out = (float*)d_out;

    const int n = in_sizes[0] / TD;
    const int m = in_sizes[1] / TD;
    const int tot = n + m;

    // fp16-MFMA path workspace: Z16 + En + per-(block,wave) partials
    const size_t z16_bytes = (size_t)tot * TD * 2;
    const size_t en_off    = (z16_bytes + 255) & ~(size_t)255;
    const size_t en_bytes  = (size_t)tot * 4;
    const size_t part_off  = ((en_off + en_bytes) + 255) & ~(size_t)255;
    const int Tm = tot / TILE;
    const int npart_m = Tm * (Tm + 1) / 2;
    const int nred = GRIDB * 8;
    const size_t needed = part_off + (size_t)nred * 8;

    if (ws_size >= needed && (tot % TILE) == 0 && (n % TILE) == 0) {
        _Float16* Z16 = (_Float16*)d_ws;
        float* En = (float*)((char*)d_ws + en_off);
        double* partials = (double*)((char*)d_ws + part_off);
        cvt_norms_kernel<<<(tot + 3) / 4, 256, 0, stream>>>(X, Y, n, tot, Z16, En);
        mmd_pipe_kernel<<<GRIDB, 512, 0, stream>>>(Z16, En, partials, n, m, Tm, npart_m);
        reduce_kernel<<<1, 256, 0, stream>>>(partials, nred, out);
    } else {
        const int T = tot / BT;
        const int npart = T * (T + 1) / 2;
        float* norms = (float*)d_ws;
        double* partials = (double*)((char*)d_ws + (((size_t)tot * 4 + 255) & ~(size_t)255));
        norms_kernel<<<(tot + 255) / 256, 256, 0, stream>>>(X, Y, n, tot, norms);
        mmd_tile_kernel<<<npart, 256, 0, stream>>>(X, Y, norms, partials, n, m, T);
        reduce_kernel<<<1, 256, 0, stream>>>(partials, npart, out);
    }
}